// Round 1
// baseline (7802.238 us; speedup 1.0000x reference)
//
#include <hip/hip_runtime.h>
#include <stdint.h>

#define SEQ  256
#define BATCH 256
#define HID  1024
#define NCLS 10

// 128 WGs: 2 row-groups (128 rows each) x 64 col-groups (16 cols each)
#define G_R 2
#define G_C 64
#define NWG (G_R * G_C)
#define ROWS_WG (BATCH / G_R)   // 128
#define COLS_WG (HID / G_C)     // 16
#define THREADS 512
#define KT (HID / 32)           // 32 k-tiles of K=32

typedef __attribute__((ext_vector_type(8))) short bf16x8;
typedef __attribute__((ext_vector_type(4))) float f32x4;

__device__ __forceinline__ unsigned short f2bf(float f) {
  unsigned u = __builtin_bit_cast(unsigned, f);
  u = (u + 0x7FFFu + ((u >> 16) & 1u)) >> 16;
  return (unsigned short)u;
}
__device__ __forceinline__ float bf2f(unsigned short h) {
  unsigned u = ((unsigned)h) << 16;
  return __builtin_bit_cast(float, u);
}
__device__ __forceinline__ float fast_tanh(float x) {
  float ax = __builtin_fabsf(x);
  float e = __expf(2.0f * ax);          // >= 1, no overflow for our range
  float t = 1.0f - 2.0f / (e + 1.0f);
  return __builtin_copysignf(t, x);
}

// h is stored k-permuted so each MFMA A-fragment (8 bf16) is one contiguous 16B load.
// MFMA 16x16x32 bf16 operand layout: lane q=(l>>4) holds k = 4q+(j&3)+16*(j>>2), j=0..7.
__device__ __forceinline__ int hperm(int n) {
  int nn = n & 31;
  int q = (nn >> 2) & 3;
  int j = (nn & 3) | ((nn >> 4) << 2);
  return (n & ~31) | (q * 8 + j);
}
__device__ __forceinline__ int hperm_inv(int s) {
  int ss = s & 31;
  int q = ss >> 3;
  int j = ss & 7;
  int kk = 4 * q + (j & 3) + 16 * (j >> 2);
  return (s & ~31) | kk;
}

__global__ __launch_bounds__(THREADS, 2) void rnn_persistent(
    const float* __restrict__ x, const float* __restrict__ Whx,
    const float* __restrict__ Whh, const float* __restrict__ Wph,
    const float* __restrict__ bh, const float* __restrict__ bp,
    float* __restrict__ out, unsigned char* __restrict__ ws)
{
  // W_hh hi-part slice as fragment-linear bf16: KT tiles * 64 lanes * 8 elems
  __shared__ unsigned short whi_lds[KT * 64 * 8];   // 16384 ushort = 32 KiB

  const int g    = blockIdx.x;
  const int tid  = threadIdx.x;
  const int lane = tid & 63;
  const int wv   = tid >> 6;       // wave 0..7
  const int l15  = lane & 15;
  const int q    = lane >> 4;

  const int r0 = (g / G_C) * ROWS_WG;     // 0 or 128
  const int n0 = (g % G_C) * COLS_WG;     // col base

  unsigned* cnt = (unsigned*)ws;
  unsigned short* wlo_g = (unsigned short*)(ws + 4096) + (size_t)g * (KT * 64 * 8);
  unsigned short* hbase = (unsigned short*)(ws + 4096 + (size_t)NWG * (KT * 64 * 8) * 2);
  const size_t PLANE = (size_t)BATCH * HID;   // elems per plane
  // planes: [buf(0/1)][hi=0/lo=1], each PLANE bf16

  // ---- prologue: stage this WG's W_hh column slice as MFMA B-fragments
  for (int idx = tid; idx < HID * COLS_WG; idx += THREADS) {
    int k = idx >> 4;          // 0..1023
    int c = idx & 15;          // local col
    float wvf = Whh[(size_t)k * HID + n0 + c];
    unsigned short hi = f2bf(wvf);
    unsigned short lo = f2bf(wvf - bf2f(hi));
    int kt = k >> 5, kk = k & 31;
    int fq = (kk >> 2) & 3;
    int fj = (kk & 3) | ((kk >> 4) << 2);
    int fl = (fq << 4) | c;
    int pos = (kt * 64 + fl) * 8 + fj;
    whi_lds[pos] = hi;
    wlo_g[pos]   = lo;
  }

  // per-lane epilogue constants
  const int n    = n0 + l15;          // actual hidden col this lane epilogues
  const float whx_v = Whx[n];
  const float bh_v  = bh[n];
  const int   npos  = hperm(n);
  const int arow  = r0 + wv * 16 + l15;   // A-fragment row (batch index)
  const int crow0 = r0 + wv * 16 + q * 4; // C rows base

  __syncthreads();

  // ---- sequential time steps
  for (int t = 0; t < SEQ; ++t) {
    const int wb = t & 1;
    f32x4 acc0 = {0.f, 0.f, 0.f, 0.f};
    f32x4 acc1 = {0.f, 0.f, 0.f, 0.f};
    f32x4 acc2 = {0.f, 0.f, 0.f, 0.f};

    if (t > 0) {
      const int rb = wb ^ 1;
      const unsigned short* Ahi = hbase + (size_t)(rb * 2 + 0) * PLANE + (size_t)arow * HID + q * 8;
      const unsigned short* Alo = Ahi + PLANE;
#pragma unroll 4
      for (int kt = 0; kt < KT; ++kt) {
        bf16x8 ahi = *(const bf16x8*)(Ahi + kt * 32);
        bf16x8 alo = *(const bf16x8*)(Alo + kt * 32);
        const int fp = (kt * 64 + lane) * 8;
        bf16x8 bhi = *(const bf16x8*)(&whi_lds[fp]);
        bf16x8 blo = *(const bf16x8*)(wlo_g + fp);
        acc0 = __builtin_amdgcn_mfma_f32_16x16x32_bf16(ahi, bhi, acc0, 0, 0, 0);
        acc1 = __builtin_amdgcn_mfma_f32_16x16x32_bf16(ahi, blo, acc1, 0, 0, 0);
        acc2 = __builtin_amdgcn_mfma_f32_16x16x32_bf16(alo, bhi, acc2, 0, 0, 0);
      }
    }

    unsigned short* Hhi = hbase + (size_t)(wb * 2 + 0) * PLANE;
    unsigned short* Hlo = Hhi + PLANE;
    {
      f32x4 s = acc0 + acc1 + acc2;
#pragma unroll
      for (int r = 0; r < 4; ++r) {
        int b = crow0 + r;
        float val = s[r] + x[b * SEQ + t] * whx_v + bh_v;
        float hv = fast_tanh(val);
        unsigned short hh = f2bf(hv);
        unsigned short hl = f2bf(hv - bf2f(hh));
        Hhi[(size_t)b * HID + npos] = hh;
        Hlo[(size_t)b * HID + npos] = hl;
      }
    }

    // ---- device-wide barrier (all NWG WGs co-resident: grid <= CU count)
    __syncthreads();
    if (tid == 0) {
      __threadfence();  // release: flush our h-tile writes to coherent point
      __hip_atomic_fetch_add(cnt, 1u, __ATOMIC_ACQ_REL, __HIP_MEMORY_SCOPE_AGENT);
      const unsigned target = (unsigned)(t + 1) * NWG;
      while (__hip_atomic_load(cnt, __ATOMIC_RELAXED, __HIP_MEMORY_SCOPE_AGENT) < target)
        __builtin_amdgcn_s_sleep(1);
      __threadfence();  // acquire: invalidate stale L1/L2 before next step's reads
    }
    __syncthreads();
  }

  // ---- final projection: out = h_last @ Wph + bp  (h_last in buf 1; barrier above synced it)
  if (wv < 2) {
    const unsigned short* Fhi = hbase + (size_t)(1 * 2 + 0) * PLANE;
    const unsigned short* Flo = Fhi + PLANE;
    int b = g * 2 + wv;                 // 128 WGs * 2 rows = 256 rows
    float p[NCLS];
#pragma unroll
    for (int c = 0; c < NCLS; ++c) p[c] = 0.f;
    for (int s = lane; s < HID; s += 64) {
      float hv = bf2f(Fhi[(size_t)b * HID + s]) + bf2f(Flo[(size_t)b * HID + s]);
      const float* wp = Wph + (size_t)hperm_inv(s) * NCLS;
#pragma unroll
      for (int c = 0; c < NCLS; ++c) p[c] += hv * wp[c];
    }
#pragma unroll
    for (int c = 0; c < NCLS; ++c) {
      float v = p[c];
      for (int off = 32; off > 0; off >>= 1) v += __shfl_down(v, off, 64);
      if (lane == 0) out[b * NCLS + c] = v + bp[c];
    }
  }
}

extern "C" void kernel_launch(void* const* d_in, const int* in_sizes, int n_in,
                              void* d_out, int out_size, void* d_ws, size_t ws_size,
                              hipStream_t stream) {
  const float* x   = (const float*)d_in[0];
  const float* Whx = (const float*)d_in[1];
  const float* Whh = (const float*)d_in[2];
  const float* Wph = (const float*)d_in[3];
  const float* bh  = (const float*)d_in[4];
  const float* bp  = (const float*)d_in[5];

  // zero the barrier counter (graph-capture-safe, deterministic per launch)
  hipMemsetAsync(d_ws, 0, 4096, stream);

  hipLaunchKernelGGL(rnn_persistent, dim3(NWG), dim3(THREADS), 0, stream,
                     x, Whx, Whh, Wph, bh, bp,
                     (float*)d_out, (unsigned char*)d_ws);
}

// Round 2
// 4093.998 us; speedup vs baseline: 1.9058x; 1.9058x over previous
//
#include <hip/hip_runtime.h>
#include <stdint.h>

#define SEQ  256
#define BATCH 256
#define HID  1024
#define NCLS 10

// 128 WGs: 4 row-groups (64 rows each) x 32 col-groups (32 cols each)
#define G_R 4
#define G_C 32
#define NWG (G_R * G_C)          // 128
#define ROWS_WG (BATCH / G_R)    // 64
#define COLS_WG (HID / G_C)      // 32
#define THREADS 512
#define KT (HID / 32)            // 32 k-tiles of K=32
#define CT (COLS_WG / 16)        // 2 col-tiles per WG

typedef __attribute__((ext_vector_type(8))) short bf16x8;
typedef __attribute__((ext_vector_type(4))) float f32x4;

__device__ __forceinline__ unsigned short f2bf(float f) {
  unsigned u = __builtin_bit_cast(unsigned, f);
  u = (u + 0x7FFFu + ((u >> 16) & 1u)) >> 16;
  return (unsigned short)u;
}
__device__ __forceinline__ float bf2f(unsigned short h) {
  unsigned u = ((unsigned)h) << 16;
  return __builtin_bit_cast(float, u);
}
__device__ __forceinline__ float fast_tanh(float x) {
  float ax = __builtin_fabsf(x);
  float e = __expf(2.0f * ax);
  float t = 1.0f - 2.0f / (e + 1.0f);
  return __builtin_copysignf(t, x);
}

// h stored k-permuted so each MFMA A-fragment (8 bf16) is one contiguous 16B load.
// MFMA 16x16x32 bf16 A/B layout: lane q=(l>>4) holds k = 4q+(j&3)+16*(j>>2), j=0..7.
// (validated by round-1 pass at absmax 9.8e-4)
__device__ __forceinline__ int hperm(int n) {
  int nn = n & 31;
  int q = (nn >> 2) & 3;
  int j = (nn & 3) | ((nn >> 4) << 2);
  return (n & ~31) | (q * 8 + j);
}
__device__ __forceinline__ int hperm_inv(int s) {
  int ss = s & 31;
  int q = ss >> 3;
  int j = ss & 7;
  int kk = 4 * q + (j & 3) + 16 * (j >> 2);
  return (s & ~31) | kk;
}

__global__ __launch_bounds__(THREADS, 2) void rnn_persistent(
    const float* __restrict__ x, const float* __restrict__ Whx,
    const float* __restrict__ Whh, const float* __restrict__ Wph,
    const float* __restrict__ bh, const float* __restrict__ bp,
    float* __restrict__ out, unsigned char* __restrict__ ws)
{
  // Full W_hh column slice (hi+lo planes) as MFMA-fragment-linear bf16.
  // [hi/lo][col-tile][kt][lane][8] = 128 KiB static LDS (gfx950 allows 160K).
  __shared__ unsigned short wlds[2][CT][KT][64][8];

  const int g    = blockIdx.x;
  const int tid  = threadIdx.x;
  const int lane = tid & 63;
  const int wv   = tid >> 6;       // wave 0..7
  const int rt   = wv >> 1;        // row tile 0..3
  const int ct   = wv & 1;         // col tile 0..1
  const int l15  = lane & 15;
  const int q    = lane >> 4;

  const int gr = g / G_C;                 // row-group 0..3
  const int r0 = gr * ROWS_WG;
  const int n0 = (g % G_C) * COLS_WG;

  unsigned* cnt = (unsigned*)ws + gr * 64;         // 256B-spaced counters
  unsigned short* hbase = (unsigned short*)(ws + 4096);
  const size_t PLANE = (size_t)BATCH * HID;        // bf16-hi plane, ping-pong x2

  // ---- prologue: stage W_hh slice as hi+lo MFMA B-fragments in LDS
  for (int idx = tid; idx < HID * COLS_WG; idx += THREADS) {
    int k = idx >> 5;          // 0..1023 (K index)
    int c = idx & 31;          // local col
    float wvf = Whh[(size_t)k * HID + n0 + c];
    unsigned short hi = f2bf(wvf);
    unsigned short lo = f2bf(wvf - bf2f(hi));
    int kt = k >> 5, kk = k & 31;
    int fq = (kk >> 2) & 3;
    int fj = (kk & 3) | ((kk >> 4) << 2);
    int fl = (fq << 4) | (c & 15);
    int cct = c >> 4;
    wlds[0][cct][kt][fl][fj] = hi;
    wlds[1][cct][kt][fl][fj] = lo;
  }

  // per-lane epilogue constants
  const int n     = n0 + ct * 16 + l15;   // hidden col this lane epilogues
  const float whx_v = Whx[n];
  const float bh_v  = bh[n];
  const int   npos  = hperm(n);
  const int arow  = r0 + rt * 16 + l15;   // A-fragment row (batch index)
  const int crow0 = r0 + rt * 16 + q * 4; // C rows base

  __syncthreads();

  // ---- sequential time steps
  for (int t = 0; t < SEQ; ++t) {
    const int wb = t & 1;
    f32x4 acc0 = {0.f, 0.f, 0.f, 0.f};
    f32x4 acc1 = {0.f, 0.f, 0.f, 0.f};

    if (t > 0) {
      const unsigned short* Ahi = hbase + (size_t)(wb ^ 1) * PLANE
                                + (size_t)arow * HID + q * 8;
#pragma unroll 8
      for (int kt = 0; kt < KT; ++kt) {
        bf16x8 a   = *(const bf16x8*)(Ahi + kt * 32);
        bf16x8 bhi = *(const bf16x8*)(&wlds[0][ct][kt][lane][0]);
        bf16x8 blo = *(const bf16x8*)(&wlds[1][ct][kt][lane][0]);
        acc0 = __builtin_amdgcn_mfma_f32_16x16x32_bf16(a, bhi, acc0, 0, 0, 0);
        acc1 = __builtin_amdgcn_mfma_f32_16x16x32_bf16(a, blo, acc1, 0, 0, 0);
      }
    }

    unsigned short* Hhi = hbase + (size_t)wb * PLANE;
    {
      f32x4 s = acc0 + acc1;
#pragma unroll
      for (int r = 0; r < 4; ++r) {
        int b = crow0 + r;
        float val = s[r] + x[b * SEQ + t] * whx_v + bh_v;
        Hhi[(size_t)b * HID + npos] = f2bf(fast_tanh(val));
      }
    }

    // ---- row-group barrier (32 WGs sharing these batch rows)
    __syncthreads();
    if (tid == 0) {
      __threadfence();  // release: make our h-tile visible device-wide
      __hip_atomic_fetch_add(cnt, 1u, __ATOMIC_ACQ_REL, __HIP_MEMORY_SCOPE_AGENT);
      const unsigned target = (unsigned)(t + 1) * G_C;
      while (__hip_atomic_load(cnt, __ATOMIC_RELAXED, __HIP_MEMORY_SCOPE_AGENT) < target)
        __builtin_amdgcn_s_sleep(1);
      __threadfence();  // acquire: drop stale L1/L2 before next step's reads
    }
    __syncthreads();
  }

  // ---- final projection: out = h_last @ Wph + bp (h_last in buf 1)
  if (wv < 2) {
    const unsigned short* Fhi = hbase + PLANE;   // wb at t=255 is 1
    int b = g * 2 + wv;                          // 128 WGs * 2 rows = 256
    float p[NCLS];
#pragma unroll
    for (int c = 0; c < NCLS; ++c) p[c] = 0.f;
    for (int s = lane; s < HID; s += 64) {
      float hv = bf2f(Fhi[(size_t)b * HID + s]);
      const float* wp = Wph + (size_t)hperm_inv(s) * NCLS;
#pragma unroll
      for (int c = 0; c < NCLS; ++c) p[c] += hv * wp[c];
    }
#pragma unroll
    for (int c = 0; c < NCLS; ++c) {
      float v = p[c];
      for (int off = 32; off > 0; off >>= 1) v += __shfl_down(v, off, 64);
      if (lane == 0) out[b * NCLS + c] = v + bp[c];
    }
  }
}

extern "C" void kernel_launch(void* const* d_in, const int* in_sizes, int n_in,
                              void* d_out, int out_size, void* d_ws, size_t ws_size,
                              hipStream_t stream) {
  const float* x   = (const float*)d_in[0];
  const float* Whx = (const float*)d_in[1];
  const float* Whh = (const float*)d_in[2];
  const float* Wph = (const float*)d_in[3];
  const float* bh  = (const float*)d_in[4];
  const float* bp  = (const float*)d_in[5];

  hipMemsetAsync(d_ws, 0, 4096, stream);   // barrier counters

  hipLaunchKernelGGL(rnn_persistent, dim3(NWG), dim3(THREADS), 0, stream,
                     x, Whx, Whh, Wph, bh, bp,
                     (float*)d_out, (unsigned char*)d_ws);
}

// Round 3
// 2728.987 us; speedup vs baseline: 2.8590x; 1.5002x over previous
//
#include <hip/hip_runtime.h>
#include <stdint.h>

#define SEQ  256
#define BATCH 256
#define HID  1024
#define NCLS 10

// 128 WGs: 4 row-groups (64 rows) x 32 col-groups (32 cols), 256 thr / 4 waves.
// Each wave computes ALL 8 tiles (4 rt x 2 ct) over its K-quarter (kt-split),
// partials reduced across waves via LDS. This cuts LDS B-reads 4x and makes
// global h-reads duplication-free.
#define G_R 4
#define G_C 32
#define NWG (G_R * G_C)         // 128
#define ROWS_WG (BATCH / G_R)   // 64
#define COLS_WG (HID / G_C)     // 32
#define THREADS 256
#define NWAVE 4
#define KT 32                   // k-tiles of K=32
#define KT_W (KT / NWAVE)       // 8 per wave
#define CT (COLS_WG / 16)       // 2

typedef __attribute__((ext_vector_type(8))) short bf16x8;
typedef __attribute__((ext_vector_type(4))) float f32x4;

__device__ __forceinline__ unsigned short f2bf(float f) {
  unsigned u = __builtin_bit_cast(unsigned, f);
  u = (u + 0x7FFFu + ((u >> 16) & 1u)) >> 16;
  return (unsigned short)u;
}
__device__ __forceinline__ float bf2f(unsigned short h) {
  unsigned u = ((unsigned)h) << 16;
  return __builtin_bit_cast(float, u);
}
__device__ __forceinline__ float fast_tanh(float x) {
  float ax = __builtin_fabsf(x);
  float e = __expf(2.0f * ax);
  float t = 1.0f - 2.0f / (e + 1.0f);
  return __builtin_copysignf(t, x);
}

// h stored k-permuted: each MFMA A-fragment (8 bf16) is one contiguous 16B load.
// 16x16x32 A/B layout: lane q=(l>>4) holds k = 4q+(j&3)+16*(j>>2). Validated r1/r2.
__device__ __forceinline__ int hperm(int n) {
  int nn = n & 31;
  int q = (nn >> 2) & 3;
  int j = (nn & 3) | ((nn >> 4) << 2);
  return (n & ~31) | (q * 8 + j);
}
__device__ __forceinline__ int hperm_inv(int s) {
  int ss = s & 31;
  int q = ss >> 3;
  int j = ss & 7;
  int kk = 4 * q + (j & 3) + 16 * (j >> 2);
  return (s & ~31) | kk;
}

__global__ __launch_bounds__(THREADS, 1) void rnn_persistent(
    const float* __restrict__ x, const float* __restrict__ Whx,
    const float* __restrict__ Whh, const float* __restrict__ Wph,
    const float* __restrict__ bh, const float* __restrict__ bp,
    float* __restrict__ out, unsigned char* __restrict__ ws)
{
  // W_hh slice, hi+lo planes, MFMA-fragment-linear: 128 KiB
  __shared__ unsigned short wlds[2][CT][KT][64][8];
  // cross-wave partial sums: producer wave w writes tiles rt!=w (3 slots): 24 KiB
  __shared__ f32x4 red[NWAVE][NWAVE - 1][CT][4][16];

  const int g    = blockIdx.x;
  const int tid  = threadIdx.x;
  const int lane = tid & 63;
  const int wv   = tid >> 6;       // wave 0..3 = K-quarter, and final owner of rt=wv
  const int l15  = lane & 15;
  const int q    = lane >> 4;

  const int gr = g >> 5;                  // row-group 0..3
  const int r0 = gr * ROWS_WG;
  const int n0 = (g & (G_C - 1)) * COLS_WG;

  unsigned* cnt = (unsigned*)ws + (size_t)gr * 64;    // 256B-spaced counters
  unsigned short* hbase = (unsigned short*)(ws + 4096);
  const size_t PLANE = (size_t)BATCH * HID;           // bf16 plane, ping-pong x2

  // ---- prologue: stage W_hh slice (hi+lo) into LDS, float4-vectorized
  for (int idx = tid; idx < HID * COLS_WG / 4; idx += THREADS) {
    int k  = idx >> 3;          // K row 0..1023
    int c4 = (idx & 7) << 2;    // local col base
    float4 v4 = *(const float4*)(Whh + (size_t)k * HID + n0 + c4);
    int kt = k >> 5, kk = k & 31;
    int fq = (kk >> 2) & 3;
    int fj = (kk & 3) | ((kk >> 4) << 2);
#pragma unroll
    for (int j = 0; j < 4; ++j) {
      int c = c4 + j;
      float w = ((const float*)&v4)[j];
      unsigned short hi = f2bf(w);
      unsigned short lo = f2bf(w - bf2f(hi));
      int fl = (fq << 4) | (c & 15);
      wlds[0][c >> 4][kt][fl][fj] = hi;
      wlds[1][c >> 4][kt][fl][fj] = lo;
    }
  }

  // per-lane epilogue constants (this lane epilogues rows of rt=wv, cols per ct)
  float whx_v[CT], bh_v[CT];
  int npos[CT];
#pragma unroll
  for (int ct = 0; ct < CT; ++ct) {
    int n = n0 + ct * 16 + l15;
    whx_v[ct] = Whx[n];
    bh_v[ct]  = bh[n];
    npos[ct]  = hperm(n);
  }
  const int crow0 = r0 + wv * 16 + q * 4;
  const int kt0 = wv * KT_W;

  __syncthreads();

  // ---- sequential time steps
  for (int t = 0; t < SEQ; ++t) {
    const int wb = t & 1;
    f32x4 acc[NWAVE][CT];
#pragma unroll
    for (int rt = 0; rt < NWAVE; ++rt)
#pragma unroll
      for (int ct = 0; ct < CT; ++ct) acc[rt][ct] = (f32x4){0.f, 0.f, 0.f, 0.f};

    if (t > 0) {
      const unsigned short* Hs = hbase + (size_t)(wb ^ 1) * PLANE;
#pragma unroll 2
      for (int kk2 = 0; kk2 < KT_W; ++kk2) {
        const int kt = kt0 + kk2;
        bf16x8 a[NWAVE];
#pragma unroll
        for (int rt = 0; rt < NWAVE; ++rt) {
          // volatile -> global_load_dwordx4 sc0 sc1: bypass L1/L2, read L3
          a[rt] = *(const volatile bf16x8*)(Hs + (size_t)(r0 + rt * 16 + l15) * HID
                                            + kt * 32 + q * 8);
        }
#pragma unroll
        for (int ct = 0; ct < CT; ++ct) {
          bf16x8 bhi = *(const bf16x8*)&wlds[0][ct][kt][lane][0];
          bf16x8 blo = *(const bf16x8*)&wlds[1][ct][kt][lane][0];
#pragma unroll
          for (int rt = 0; rt < NWAVE; ++rt) {
            acc[rt][ct] = __builtin_amdgcn_mfma_f32_16x16x32_bf16(a[rt], bhi, acc[rt][ct], 0, 0, 0);
            acc[rt][ct] = __builtin_amdgcn_mfma_f32_16x16x32_bf16(a[rt], blo, acc[rt][ct], 0, 0, 0);
          }
        }
      }
    }

    // ---- partials for non-owned tiles -> LDS; keep own rt=wv in regs (static idx)
    f32x4 own[CT];
#pragma unroll
    for (int rt = 0; rt < NWAVE; ++rt) {
      if (rt == wv) {
#pragma unroll
        for (int ct = 0; ct < CT; ++ct) own[ct] = acc[rt][ct];
      } else {
        int slot = rt < wv ? rt : rt - 1;
#pragma unroll
        for (int ct = 0; ct < CT; ++ct) red[wv][slot][ct][q][l15] = acc[rt][ct];
      }
    }
    __syncthreads();

    // ---- reduce own tiles + epilogue
    unsigned short* Hd = hbase + (size_t)wb * PLANE;
    float xr[4];
#pragma unroll
    for (int r = 0; r < 4; ++r) xr[r] = x[(size_t)(crow0 + r) * SEQ + t];

#pragma unroll
    for (int ct = 0; ct < CT; ++ct) {
      f32x4 s = own[ct];
#pragma unroll
      for (int w2 = 0; w2 < NWAVE; ++w2) {
        if (w2 != wv) {
          int slot = wv < w2 ? wv : wv - 1;
          s += red[w2][slot][ct][q][l15];
        }
      }
#pragma unroll
      for (int r = 0; r < 4; ++r) {
        float val = s[r] + xr[r] * whx_v[ct] + bh_v[ct];
        unsigned short hv = f2bf(fast_tanh(val));
        // write-through to L3 (sc0 sc1), never dirty in L2 -> no flush needed
        __hip_atomic_store(Hd + (size_t)(crow0 + r) * HID + npos[ct], hv,
                           __ATOMIC_RELAXED, __HIP_MEMORY_SCOPE_AGENT);
      }
    }

    // ---- row-group barrier, NO cache-flush fences.
    // __syncthreads drains each wave's vmcnt before s_barrier, so all h stores
    // are at the coherence point (L3) before tid0 increments the counter.
    __syncthreads();
    if (tid == 0) {
      __hip_atomic_fetch_add(cnt, 1u, __ATOMIC_RELAXED, __HIP_MEMORY_SCOPE_AGENT);
      const unsigned target = (unsigned)(t + 1) * G_C;
      while (__hip_atomic_load(cnt, __ATOMIC_RELAXED, __HIP_MEMORY_SCOPE_AGENT) < target)
        __builtin_amdgcn_s_sleep(1);
    }
    __syncthreads();
  }

  // ---- final projection: out = h_last @ Wph + bp (h_last in plane 1)
  if (wv < 2) {
    const unsigned short* F = hbase + PLANE;
    int b = g * 2 + wv;                 // row b is in our own row-group (b>>6 == gr)
    float p[NCLS];
#pragma unroll
    for (int c = 0; c < NCLS; ++c) p[c] = 0.f;
    for (int s = lane; s < HID; s += 64) {
      unsigned short hraw = __hip_atomic_load(F + (size_t)b * HID + s,
                                              __ATOMIC_RELAXED, __HIP_MEMORY_SCOPE_AGENT);
      float hv = bf2f(hraw);
      const float* wp = Wph + (size_t)hperm_inv(s) * NCLS;
#pragma unroll
      for (int c = 0; c < NCLS; ++c) p[c] += hv * wp[c];
    }
#pragma unroll
    for (int c = 0; c < NCLS; ++c) {
      float v = p[c];
      for (int off = 32; off > 0; off >>= 1) v += __shfl_down(v, off, 64);
      if (lane == 0) out[b * NCLS + c] = v + bp[c];
    }
  }
}

extern "C" void kernel_launch(void* const* d_in, const int* in_sizes, int n_in,
                              void* d_out, int out_size, void* d_ws, size_t ws_size,
                              hipStream_t stream) {
  const float* x   = (const float*)d_in[0];
  const float* Whx = (const float*)d_in[1];
  const float* Whh = (const float*)d_in[2];
  const float* Wph = (const float*)d_in[3];
  const float* bh  = (const float*)d_in[4];
  const float* bp  = (const float*)d_in[5];

  hipMemsetAsync(d_ws, 0, 4096, stream);   // barrier counters

  hipLaunchKernelGGL(rnn_persistent, dim3(NWG), dim3(THREADS), 0, stream,
                     x, Whx, Whh, Wph, bh, bp,
                     (float*)d_out, (unsigned char*)d_ws);
}